// Round 1
// baseline (236.280 us; speedup 1.0000x reference)
//
#include <hip/hip_runtime.h>
#include <hip/hip_fp16.h>
#include <math.h>

// Problem constants
#define NN   512
#define FF   2048
#define DMM  512
#define EH   65536
#define LAMF 5.0f
#define SVF  0.36787944117144233f   // exp(-0.2*5) = exp(-1)

__device__ __forceinline__ float sigmoidf_(float x) { return 1.0f / (1.0f + expf(-x)); }

// ---------------- generic fp32 tiled GEMM: C = [relu](A@B [+bias]) ----------
// A: MxK row-major, B: KxN row-major, C: MxN. M,N,K multiples of 32.
template<bool RELU, bool BIAS>
__global__ __launch_bounds__(256) void gemm32(const float* __restrict__ A,
    const float* __restrict__ B, const float* __restrict__ bias,
    float* __restrict__ C, int M, int N, int K)
{
    __shared__ float As[32][33], Bs[32][33];
    const int tid = threadIdx.x;
    const int row0 = blockIdx.y << 5, col0 = blockIdx.x << 5;
    const int lr = tid >> 3, lc = (tid & 7) << 2;
    const int tx = tid & 15, ty = tid >> 4;
    float a00 = 0.f, a01 = 0.f, a10 = 0.f, a11 = 0.f;
    for (int k0 = 0; k0 < K; k0 += 32) {
        float4 va = *(const float4*)&A[(size_t)(row0 + lr) * K + k0 + lc];
        As[lr][lc] = va.x; As[lr][lc+1] = va.y; As[lr][lc+2] = va.z; As[lr][lc+3] = va.w;
        float4 vb = *(const float4*)&B[(size_t)(k0 + lr) * N + col0 + lc];
        Bs[lr][lc] = vb.x; Bs[lr][lc+1] = vb.y; Bs[lr][lc+2] = vb.z; Bs[lr][lc+3] = vb.w;
        __syncthreads();
        #pragma unroll
        for (int kk = 0; kk < 32; ++kk) {
            float x0 = As[ty*2][kk], x1 = As[ty*2+1][kk];
            float y0 = Bs[kk][tx*2], y1 = Bs[kk][tx*2+1];
            a00 += x0*y0; a01 += x0*y1; a10 += x1*y0; a11 += x1*y1;
        }
        __syncthreads();
    }
    const int r0 = row0 + ty*2, c0 = col0 + tx*2;
    float b0 = BIAS ? bias[c0] : 0.f, b1 = BIAS ? bias[c0+1] : 0.f;
    float v00 = a00 + b0, v01 = a01 + b1, v10 = a10 + b0, v11 = a11 + b1;
    if (RELU) { v00 = fmaxf(v00, 0.f); v01 = fmaxf(v01, 0.f);
                v10 = fmaxf(v10, 0.f); v11 = fmaxf(v11, 0.f); }
    C[(size_t)r0*N + c0]     = v00; C[(size_t)r0*N + c0 + 1]     = v01;
    C[(size_t)(r0+1)*N + c0] = v10; C[(size_t)(r0+1)*N + c0 + 1] = v11;
}

// ---------------- geo tiny GEMM: geoA = coords@W1[0:4]+b1, geoB = coords@W1[4:8]
__global__ __launch_bounds__(256) void geo_kernel(const float* __restrict__ coords,
    const float* __restrict__ geo_W1, const float* __restrict__ geo_b1,
    float* __restrict__ geoA, float* __restrict__ geoB)
{
    int idx = blockIdx.x * 256 + threadIdx.x;      // < 2*512*64 = 65536
    int half = idx >> 15;
    int rem  = idx & 32767;
    int n = rem >> 6, j = rem & 63;
    float4 cv = *(const float4*)&coords[n * 4];
    const float* W = geo_W1 + half * 4 * 64;
    float v = cv.x * W[j] + cv.y * W[64 + j] + cv.z * W[128 + j] + cv.w * W[192 + j];
    if (half == 0) geoA[n * 64 + j] = v + geo_b1[j];
    else           geoB[n * 64 + j] = v;
}

// ---------------- per-edge: ew (both halves) + iou (first half) -------------
__global__ __launch_bounds__(256) void edge_kernel(
    const float* __restrict__ Aapp, const float* __restrict__ Bapp,
    const float* __restrict__ geoA, const float* __restrict__ geoB,
    const float* __restrict__ app_w2, const float* __restrict__ app_b2,
    const float* __restrict__ geo_w2, const float* __restrict__ geo_b2,
    const float* __restrict__ aff_w, const float* __restrict__ aff_b,
    const float* __restrict__ co, float* __restrict__ ew, float* __restrict__ iou1)
{
    __shared__ float sA[16][129], sB[16][129], sGA[16][65], sGB[16][65];
    __shared__ float sw2[128], sgw2[64];
    const int tid = threadIdx.x;
    const int half = blockIdx.z;
    const int t0 = blockIdx.y * 16, d0 = blockIdx.x * 16;
    const int sbase = half ? (256 + d0) : t0;   // rows of Aapp (source nodes)
    const int dbase = half ? t0 : (256 + d0);   // rows of Bapp (dest nodes)
    for (int i = tid; i < 16 * 32; i += 256) {
        int rr = i >> 5, c4 = (i & 31) << 2;
        float4 va = *(const float4*)&Aapp[(sbase + rr) * 128 + c4];
        sA[rr][c4] = va.x; sA[rr][c4+1] = va.y; sA[rr][c4+2] = va.z; sA[rr][c4+3] = va.w;
        float4 vb = *(const float4*)&Bapp[(dbase + rr) * 128 + c4];
        sB[rr][c4] = vb.x; sB[rr][c4+1] = vb.y; sB[rr][c4+2] = vb.z; sB[rr][c4+3] = vb.w;
    }
    for (int i = tid; i < 16 * 16; i += 256) {
        int rr = i >> 4, c4 = (i & 15) << 2;
        float4 va = *(const float4*)&geoA[(sbase + rr) * 64 + c4];
        sGA[rr][c4] = va.x; sGA[rr][c4+1] = va.y; sGA[rr][c4+2] = va.z; sGA[rr][c4+3] = va.w;
        float4 vb = *(const float4*)&geoB[(dbase + rr) * 64 + c4];
        sGB[rr][c4] = vb.x; sGB[rr][c4+1] = vb.y; sGB[rr][c4+2] = vb.z; sGB[rr][c4+3] = vb.w;
    }
    if (tid < 128) sw2[tid] = app_w2[tid];
    else if (tid < 192) sgw2[tid - 128] = geo_w2[tid - 128];
    __syncthreads();
    const int tx = tid & 15, ty = tid >> 4;     // ty: t-local, tx: d-local
    const int si = half ? tx : ty;              // index into sA
    const int di = half ? ty : tx;              // index into sB
    float acc1 = 0.f;
    #pragma unroll 8
    for (int j = 0; j < 128; ++j) {
        float v = sA[si][j] + sB[di][j];
        acc1 += fmaxf(v, 0.f) * sw2[j];
    }
    float x1 = sigmoidf_(acc1 + app_b2[0]);
    float acc2 = 0.f;
    #pragma unroll 8
    for (int j = 0; j < 64; ++j) {
        float v = sGA[si][j] + sGB[di][j];
        acc2 += fmaxf(v, 0.f) * sgw2[j];
    }
    float x2 = sigmoidf_(acc2 + geo_b2[0]);
    float e = sigmoidf_(x1 * aff_w[0] + x2 * aff_w[1] + aff_b[0]);
    const int t = t0 + ty, d = d0 + tx;
    ew[half * EH + t * 256 + d] = e;
    if (half == 0) {
        float4 a = *(const float4*)&co[t * 4];
        float4 b = *(const float4*)&co[(256 + d) * 4];
        float ltx = fmaxf(a.x, b.x), lty = fmaxf(a.y, b.y);
        float rbx = fminf(a.z, b.z), rby = fminf(a.w, b.w);
        float w  = fmaxf(rbx - ltx, 0.f), hh = fmaxf(rby - lty, 0.f);
        float inter = w * hh;
        float areaA = (a.z - a.x) * (a.w - a.y);
        float areaB = (b.z - b.x) * (b.w - b.y);
        iou1[t * 256 + d] = inter / (areaA + areaB - inter + 1e-6f);
    }
}

// ---------------- out = relu(Hs + agg + b_mp), agg = segment GEMM (K=256) ---
__global__ __launch_bounds__(256) void agg_out_kernel(const float* __restrict__ ew,
    const float* __restrict__ Hn, const float* __restrict__ Hs,
    const float* __restrict__ b_mp, float* __restrict__ outm)
{
    __shared__ float sA[32][33], sB[32][33];
    const int tid = threadIdx.x;
    const int n0 = blockIdx.y << 5, c0 = blockIdx.x << 5;
    const bool trk = (n0 < 256);
    const int lr = tid >> 3, lc = (tid & 7) << 2;
    const int tx = tid & 15, ty = tid >> 4;
    float a00 = 0.f, a01 = 0.f, a10 = 0.f, a11 = 0.f;
    for (int k0 = 0; k0 < 256; k0 += 32) {
        if (trk) {  // A[n][k] = ew[EH + n*256 + k]  (contiguous rows)
            float4 v = *(const float4*)&ew[EH + (n0 + lr) * 256 + k0 + lc];
            sA[lr][lc] = v.x; sA[lr][lc+1] = v.y; sA[lr][lc+2] = v.z; sA[lr][lc+3] = v.w;
        } else {    // A[n][k] = ew[k*256 + (n-256)]  (transposed staging)
            float4 v = *(const float4*)&ew[(k0 + lr) * 256 + (n0 - 256) + lc];
            sA[lc+0][lr] = v.x; sA[lc+1][lr] = v.y; sA[lc+2][lr] = v.z; sA[lc+3][lr] = v.w;
        }
        int hrow = trk ? (256 + k0 + lr) : (k0 + lr);
        float4 vb = *(const float4*)&Hn[hrow * 512 + c0 + lc];
        sB[lr][lc] = vb.x; sB[lr][lc+1] = vb.y; sB[lr][lc+2] = vb.z; sB[lr][lc+3] = vb.w;
        __syncthreads();
        #pragma unroll
        for (int kk = 0; kk < 32; ++kk) {
            float x0 = sA[ty*2][kk], x1 = sA[ty*2+1][kk];
            float y0 = sB[kk][tx*2], y1 = sB[kk][tx*2+1];
            a00 += x0*y0; a01 += x0*y1; a10 += x1*y0; a11 += x1*y1;
        }
        __syncthreads();
    }
    const int n = n0 + ty*2, cc = c0 + tx*2;
    float r00 = a00 + Hs[n*512 + cc]     + b_mp[cc];
    float r01 = a01 + Hs[n*512 + cc + 1] + b_mp[cc + 1];
    float r10 = a10 + Hs[(n+1)*512 + cc]     + b_mp[cc];
    float r11 = a11 + Hs[(n+1)*512 + cc + 1] + b_mp[cc + 1];
    outm[n*512 + cc]       = fmaxf(r00, 0.f);
    outm[n*512 + cc + 1]   = fmaxf(r01, 0.f);
    outm[(n+1)*512 + cc]   = fmaxf(r10, 0.f);
    outm[(n+1)*512 + cc+1] = fmaxf(r11, 0.f);
}

// ---------------- row norms of outm ----------------------------------------
__global__ __launch_bounds__(256) void norm_kernel(const float* __restrict__ outm,
    float* __restrict__ norms)
{
    const int w = (blockIdx.x * 256 + threadIdx.x) >> 6;   // row = global wave id
    const int lane = threadIdx.x & 63;
    const float* rp = &outm[w * 512];
    float s = 0.f;
    #pragma unroll
    for (int i = 0; i < 8; ++i) { float v = rp[i * 64 + lane]; s += v * v; }
    #pragma unroll
    for (int o = 32; o > 0; o >>= 1) s += __shfl_down(s, o);
    if (lane == 0) norms[w] = fmaxf(sqrtf(s), 1e-6f);
}

// ---------------- Gram + fin + M0 (fp16) ------------------------------------
__global__ __launch_bounds__(256) void gram_kernel(const float* __restrict__ outm,
    const float* __restrict__ norms, const float* __restrict__ iou1,
    const float* __restrict__ fin_w, const float* __restrict__ fin_b,
    __half* __restrict__ Mh)
{
    __shared__ float sA[32][33], sB[32][33];
    const int tid = threadIdx.x;
    const int t0 = blockIdx.y << 5, d0 = blockIdx.x << 5;
    const int lr = tid >> 3, lc = (tid & 7) << 2;
    const int tx = tid & 15, ty = tid >> 4;
    float a00 = 0.f, a01 = 0.f, a10 = 0.f, a11 = 0.f;
    for (int k0 = 0; k0 < 512; k0 += 32) {
        float4 va = *(const float4*)&outm[(t0 + lr) * 512 + k0 + lc];
        sA[lr][lc] = va.x; sA[lr][lc+1] = va.y; sA[lr][lc+2] = va.z; sA[lr][lc+3] = va.w;
        float4 vb = *(const float4*)&outm[(256 + d0 + lr) * 512 + k0 + lc];
        sB[lc+0][lr] = vb.x; sB[lc+1][lr] = vb.y; sB[lc+2][lr] = vb.z; sB[lc+3][lr] = vb.w;
        __syncthreads();
        #pragma unroll
        for (int kk = 0; kk < 32; ++kk) {
            float x0 = sA[ty*2][kk], x1 = sA[ty*2+1][kk];
            float y0 = sB[kk][tx*2], y1 = sB[kk][tx*2+1];
            a00 += x0*y0; a01 += x0*y1; a10 += x1*y0; a11 += x1*y1;
        }
        __syncthreads();
    }
    const float fw0 = fin_w[0], fw1 = fin_w[1], fb = fin_b[0];
    const int t = t0 + ty*2, d = d0 + tx*2;
    float accs[2][2] = {{a00, a01}, {a10, a11}};
    #pragma unroll
    for (int i = 0; i < 2; ++i)
        #pragma unroll
        for (int j = 0; j < 2; ++j) {
            int tt = t + i, dd = d + j;
            float cosv = accs[i][j] / (norms[tt] * norms[256 + dd]);
            float fin = sigmoidf_(cosv * fw0 + iou1[tt * 256 + dd] * fw1 + fb);
            Mh[tt * 256 + dd] = __float2half(expf(fin * LAMF));
        }
}

// ---------------- Sinkhorn: single block, M0 fp16 in LDS --------------------
// M = diag(r) M0 diag(c); 8 iterations of r = 1/(M0 c), c = 1/(M0^T r),
// borders (slack row/col = SVF) handled analytically.
#define SINK_LDS (256 * 258 * 2 + (257 + 257 + 16) * 4)
__global__ __launch_bounds__(512) void sinkhorn_kernel(const __half* __restrict__ Mh,
    float* __restrict__ gr, float* __restrict__ gc)
{
    extern __shared__ char smem[];
    __half* Ms = (__half*)smem;                       // [256][258]
    float* r   = (float*)(smem + 256 * 258 * 2);      // [257]
    float* c   = r + 257;                             // [257]
    float* red = c + 257;                             // scratch
    const int tid = threadIdx.x;
    // load M0 interior (65536 halves) into LDS
    for (int i = tid; i < 8192; i += 512) {
        uint4 v = ((const uint4*)Mh)[i];              // 8 halves
        int t = i >> 5, d = (i & 31) << 3;
        uint* dst = (uint*)&Ms[t * 258 + d];
        dst[0] = v.x; dst[1] = v.y; dst[2] = v.z; dst[3] = v.w;
    }
    if (tid <= 256) c[tid] = 1.0f;
    if (tid == 0) red[8] = 257.0f;                    // S_c for c==1
    __syncthreads();

    for (int it = 0; it < 8; ++it) {
        // ---- row phase: r[t] = 1/(sum_d M0[t][d] c[d] + SV*c[256])
        {
            float c256 = c[256];
            float Sc = red[8];
            int row = tid >> 1, sub = tid & 1;
            const __half2* rp = (const __half2*)&Ms[row * 258 + sub * 128];
            const float* cp = &c[sub * 128];
            float acc = 0.f;
            #pragma unroll 8
            for (int p = 0; p < 64; ++p) {
                float2 f = __half22float2(rp[p]);
                acc += f.x * cp[2*p] + f.y * cp[2*p + 1];
            }
            acc += __shfl_xor(acc, 1);
            if (sub == 0) r[row] = 1.0f / (acc + SVF * c256);
            if (tid == 511) r[256] = 1.0f / (SVF * Sc);
        }
        __syncthreads();
        if (tid < 64) {  // S_r = sum r[0..256]
            float s = r[tid] + r[tid + 64] + r[tid + 128] + r[tid + 192];
            if (tid == 0) s += r[256];
            #pragma unroll
            for (int o = 32; o > 0; o >>= 1) s += __shfl_down(s, o);
            if (tid == 0) red[9] = s;
        }
        __syncthreads();
        // ---- col phase: c[d] = 1/(sum_t M0[t][d] r[t] + SV*r[256])
        {
            float r256 = r[256];
            float Sr = red[9];
            int dp = tid >> 2, sub = tid & 3;         // dp: col pair, sub: t-chunk
            const __half* base = &Ms[(sub * 64) * 258 + 2 * dp];
            float a0 = 0.f, a1 = 0.f;
            #pragma unroll 8
            for (int k = 0; k < 64; ++k) {
                float2 f = __half22float2(*(const __half2*)(base + k * 258));
                float rv = r[sub * 64 + k];
                a0 += f.x * rv; a1 += f.y * rv;
            }
            a0 += __shfl_xor(a0, 1); a0 += __shfl_xor(a0, 2);
            a1 += __shfl_xor(a1, 1); a1 += __shfl_xor(a1, 2);
            if (sub == 0) {
                c[2*dp]     = 1.0f / (a0 + SVF * r256);
                c[2*dp + 1] = 1.0f / (a1 + SVF * r256);
            }
            if (tid == 511) c[256] = 1.0f / (SVF * Sr);
        }
        __syncthreads();
        if (tid < 64) {  // S_c = sum c[0..256]
            float s = c[tid] + c[tid + 64] + c[tid + 128] + c[tid + 192];
            if (tid == 0) s += c[256];
            #pragma unroll
            for (int o = 32; o > 0; o >>= 1) s += __shfl_down(s, o);
            if (tid == 0) red[8] = s;
        }
        __syncthreads();
    }
    if (tid <= 256) { gr[tid] = r[tid]; gc[tid] = c[tid]; }
}

// ---------------- final assembly of d_out ------------------------------------
__global__ __launch_bounds__(256) void final_kernel(const __half* __restrict__ Mh,
    const float* __restrict__ r, const float* __restrict__ c,
    const float* __restrict__ gt, float* __restrict__ out)
{
    const int bid = blockIdx.x, tid = threadIdx.x;
    if (bid < 256) {
        int k = bid * 256 + tid;
        out[k] = __half2float(Mh[k]) * r[bid] * c[tid];
    } else if (bid < 512) {
        int k = (bid - 256) * 256 + tid;
        out[EH + k] = gt[k];
    } else if (tid == 0) {
        out[2 * EH]     = 256.0f;   // det_num = D
        out[2 * EH + 1] = 256.0f;   // tracklet_num = T
    }
}

extern "C" void kernel_launch(void* const* d_in, const int* in_sizes, int n_in,
                              void* d_out, int out_size, void* d_ws, size_t ws_size,
                              hipStream_t stream)
{
    const float* x       = (const float*)d_in[0];
    const float* coords  = (const float*)d_in[1];
    const float* co      = (const float*)d_in[2];
    const float* gt      = (const float*)d_in[3];
    // d_in[4] = edge_index (structure known analytically)
    const float* W_enc   = (const float*)d_in[5];
    const float* b_enc   = (const float*)d_in[6];
    const float* app_W1  = (const float*)d_in[7];
    const float* app_b1  = (const float*)d_in[8];
    const float* app_w2  = (const float*)d_in[9];
    const float* app_b2  = (const float*)d_in[10];
    const float* geo_W1  = (const float*)d_in[11];
    const float* geo_b1  = (const float*)d_in[12];
    const float* geo_w2  = (const float*)d_in[13];
    const float* geo_b2  = (const float*)d_in[14];
    const float* aff_w   = (const float*)d_in[15];
    const float* aff_b   = (const float*)d_in[16];
    const float* W_self  = (const float*)d_in[17];
    const float* W_nbr   = (const float*)d_in[18];
    const float* b_mp    = (const float*)d_in[19];
    const float* fin_w   = (const float*)d_in[20];
    const float* fin_b   = (const float*)d_in[21];
    float* out = (float*)d_out;

    float* ws = (float*)d_ws;
    float* h     = ws;                  // 512*512
    float* Hn    = ws + 262144;
    float* Hs    = ws + 524288;
    float* Aapp  = ws + 786432;         // 512*128
    float* Bapp  = ws + 851968;
    float* geoA  = ws + 917504;         // 512*64
    float* geoB  = ws + 950272;
    float* ewb   = ws + 983040;         // 131072
    float* iou1  = ws + 1114112;        // 65536
    float* outm  = ws + 1179648;        // 512*512
    float* norms = ws + 1441792;        // 512
    __half* Mh   = (__half*)(ws + 1442304);  // 65536 halves
    float* gr    = ws + 1475072;        // 257
    float* gc    = ws + 1475329;        // 257

    // 1) h = relu(x @ W_enc + b_enc)          512x512, K=2048
    gemm32<true, true><<<dim3(16, 16), 256, 0, stream>>>(x, W_enc, b_enc, h, 512, 512, 2048);
    // 2) Aapp = h @ app_W1[:512] + app_b1     512x128, K=512
    gemm32<false, true><<<dim3(4, 16), 256, 0, stream>>>(h, app_W1, app_b1, Aapp, 512, 128, 512);
    // 3) Bapp = h @ app_W1[512:]              512x128, K=512
    gemm32<false, false><<<dim3(4, 16), 256, 0, stream>>>(h, app_W1 + 512 * 128, nullptr, Bapp, 512, 128, 512);
    // 4) Hn = h @ W_nbr                       512x512, K=512
    gemm32<false, false><<<dim3(16, 16), 256, 0, stream>>>(h, W_nbr, nullptr, Hn, 512, 512, 512);
    // 5) Hs = h @ W_self
    gemm32<false, false><<<dim3(16, 16), 256, 0, stream>>>(h, W_self, nullptr, Hs, 512, 512, 512);
    // 6) geoA/geoB
    geo_kernel<<<256, 256, 0, stream>>>(coords, geo_W1, geo_b1, geoA, geoB);
    // 7) per-edge ew + iou
    edge_kernel<<<dim3(16, 16, 2), 256, 0, stream>>>(Aapp, Bapp, geoA, geoB,
        app_w2, app_b2, geo_w2, geo_b2, aff_w, aff_b, co, ewb, iou1);
    // 8) out = relu(Hs + agg + b_mp)
    agg_out_kernel<<<dim3(16, 16), 256, 0, stream>>>(ewb, Hn, Hs, b_mp, outm);
    // 9) row norms
    norm_kernel<<<128, 256, 0, stream>>>(outm, norms);
    // 10) Gram + fin + M0(fp16)
    gram_kernel<<<dim3(8, 8), 256, 0, stream>>>(outm, norms, iou1, fin_w, fin_b, Mh);
    // 11) Sinkhorn scale vectors
    hipFuncSetAttribute(reinterpret_cast<const void*>(sinkhorn_kernel),
                        hipFuncAttributeMaxDynamicSharedMemorySize, SINK_LDS);
    sinkhorn_kernel<<<1, 512, SINK_LDS, stream>>>(Mh, gr, gc);
    // 12) final output assembly
    final_kernel<<<513, 256, 0, stream>>>(Mh, gr, gc, gt, out);
}